// Round 11
// baseline (245.985 us; speedup 1.0000x reference)
//
#include <hip/hip_runtime.h>

// ---------------------------------------------------------------------------
// MHA forward, fp32 I/O.  S=4096, D=1024, NH=16, HD=64.
// R23 = R22's counted-vmcnt GEMM ring with the race FIXED.  Diagnosis: all
// R17-R22 failures showed pytest-absmax small but graph-replay absmax 468
// -> timing-dependent races, not math.  R22's race: with a RAW s_barrier,
// the compiler may sink register-only MFMAs (and their lgkmcnt waits) past
// the barrier asm, so a wave can cross the barrier with ds_reads issued
// but NOT yet executed; another wave's post-barrier global_load_lds then
// overwrites the buffer before those reads execute.  (__syncthreads is
// safe precisely because it drains lgkmcnt+vmcnt first.)  Fix: explicit
// s_waitcnt lgkmcnt(0) at the END of each K-step, before the next raw
// barrier -- pins read execution pre-barrier at ~zero cost, while keeping
// the point of the design: vmcnt never drains to 0 mid-loop, so next-tile
// global_load_lds stay in flight across barriers (T4).  3-buffer ring,
// stage tile it+2 after the barrier that retires reads of that buffer.
// attn = R20 green body.  Math unchanged everywhere.
// ---------------------------------------------------------------------------

typedef unsigned short ushort_t;
typedef unsigned short ushort4v __attribute__((ext_vector_type(4)));
typedef unsigned short ushort8 __attribute__((ext_vector_type(8)));
typedef __bf16 bf16x8 __attribute__((ext_vector_type(8)));
typedef float f32x4 __attribute__((ext_vector_type(4)));
typedef float f32x16 __attribute__((ext_vector_type(16)));
typedef unsigned int uint4v __attribute__((ext_vector_type(4)));

#define SEQ 4096
#define DIM 1024
#define NH 16
#define HD 64
// 0.125 * log2(e): folded into Q projection so softmax uses exp2 directly
#define QSCALE 0.18033688011112042f

__device__ inline ushort_t fcvt(float f) {           // native f32->bf16 RTNE
    return __builtin_bit_cast(ushort_t, (__bf16)f);
}
__device__ inline bf16x8 frag_of(ushort8 t) {
    return __builtin_bit_cast(bf16x8, t);
}
__device__ inline bf16x8 lds_frag(const ushort_t* p) {
    return frag_of(*(const ushort8*)p);
}
__device__ inline unsigned pk2(float a, float b) {   // packed bf16 pair
    return (unsigned)fcvt(a) | ((unsigned)fcvt(b) << 16);
}
// swap lanes 32-63 of a with lanes 0-31 of b (gfx950 cross-lane op)
__device__ inline void plswap(unsigned& a, unsigned& b) {
    asm("v_permlane32_swap_b32 %0, %1" : "+v"(a), "+v"(b));
}
// swizzled elem offset within a linear [64][64] bf16 LDS tile (attn)
__device__ inline int swz(int row, int col) {
    return row * 64 + (col ^ ((row & 7) << 3));
}
// XCD-aware chunked remap (bijective, nwg % 8 == 0)
__device__ inline int xcd_swz(int bid, int nwg) {
    return (bid & 7) * (nwg >> 3) + (bid >> 3);
}
// async global->LDS, 16B per lane; LDS dest = wave-uniform base + lane*16
__device__ __attribute__((always_inline)) inline void gload16(
    const ushort_t* g, ushort_t* l)
{
    __builtin_amdgcn_global_load_lds(
        (const __attribute__((address_space(1))) void*)g,
        (__attribute__((address_space(3))) void*)l, 16, 0, 0);
}

// ---------------------------------------------------------------------------
// Prep: f32 -> bf16 converts (R16-exact)
// ---------------------------------------------------------------------------
__global__ __launch_bounds__(256) void cvt2(
    const float* __restrict__ s0, ushort_t* __restrict__ d0,
    const float* __restrict__ s1, ushort_t* __restrict__ d1, int n8)
{
    const float* s = blockIdx.y ? s1 : s0;
    ushort_t*    d = blockIdx.y ? d1 : d0;
    int i = blockIdx.x * 256 + threadIdx.x;
    if (i >= n8) return;
    const f32x4* sp = (const f32x4*)s + (size_t)i * 2;
    f32x4 a = sp[0], b = sp[1];
    ushort8 o;
    for (int k = 0; k < 4; ++k) { o[k] = fcvt(a[k]); o[k + 4] = fcvt(b[k]); }
    *((ushort8*)d + i) = o;
}

__global__ __launch_bounds__(256) void cvt4(
    const float* __restrict__ s0, ushort_t* __restrict__ d0,
    const float* __restrict__ s1, ushort_t* __restrict__ d1,
    const float* __restrict__ s2, ushort_t* __restrict__ d2,
    const float* __restrict__ s3, ushort_t* __restrict__ d3, int n8)
{
    const float* ss[4] = {s0, s1, s2, s3};
    ushort_t*    dd[4] = {d0, d1, d2, d3};
    const float* s = ss[blockIdx.y];
    ushort_t*    d = dd[blockIdx.y];
    int i = blockIdx.x * 256 + threadIdx.x;
    if (i >= n8) return;
    const f32x4* sp = (const f32x4*)s + (size_t)i * 2;
    f32x4 a = sp[0], b = sp[1];
    ushort8 o;
    for (int k = 0; k < 4; ++k) { o[k] = fcvt(a[k]); o[k + 4] = fcvt(b[k]); }
    *((ushort8*)d + i) = o;
}

// ---------------------------------------------------------------------------
// R23 GEMM core.  Tile BM x BN, BK=32, 4 waves 2x2, 3-buffer ring.
// Per K-step: {vmcnt(LPW) [own tile-it loads retired; tile it+1 stays in
// flight], s_barrier, stage tile it+2 into retired buffer, ds_read+MFMA,
// lgkmcnt(0) [pin read EXECUTION before next barrier -- race fix]}.
// Staging geometry and read-side swizzle identical to R16 (green).
// ---------------------------------------------------------------------------
template<int BM, int BN>
__device__ __attribute__((always_inline)) inline void gemm_core4(
    const ushort_t* __restrict__ A, const ushort_t* __restrict__ W,
    int m0, int n0, int tid, f32x4 (&acc)[BM / 32][BN / 32], ushort_t* sLDS)
{
    constexpr int TA  = BM * 32;           // A tile elems
    constexpr int TB  = BN * 32;           // B tile elems
    constexpr int TT  = TA + TB;           // one ring buffer
    constexpr int LPW = BM / 64 + BN / 64; // gl_lds per wave per step
    constexpr int NST = DIM / 32;          // K-steps

    const int w    = tid >> 6;
    const int lane = tid & 63;
    const int quad = lane >> 4;
    const int l15  = lane & 15;
    const int wm   = w >> 1;
    const int wn   = w & 1;

    // staging: 4 lanes/row, 16 rows per gload; source chunk swizzled
    const int srow = lane >> 2;                        // 0..15
    const int sch  = (((lane & 3) ^ ((lane >> 3) & 3)) << 3);  // elems
    const ushort_t* Ag = A + (size_t)(m0 + w * (BM / 4) + srow) * DIM + sch;
    const ushort_t* Bg = W + (size_t)(n0 + w * (BN / 4) + srow) * DIM + sch;
    const int aOff = w * (BM / 4) * 32;    // elems
    const int bOff = w * (BN / 4) * 32;

    ushort_t* b0 = sLDS;                   // compute buffer (tile it)
    ushort_t* b1 = sLDS + TT;              // tile it+1 (loads in flight)
    ushort_t* b2 = sLDS + 2 * TT;          // tile it+2 (staged this iter)

#define STAGE4(buf, k0)                                                     \
    do {                                                                    \
        for (int i = 0; i < BM / 64; ++i)                                   \
            gload16(Ag + (k0) + (size_t)(i * 16) * DIM,                     \
                    (buf) + aOff + i * 512);                                \
        for (int i = 0; i < BN / 64; ++i)                                   \
            gload16(Bg + (k0) + (size_t)(i * 16) * DIM,                     \
                    (buf) + TA + bOff + i * 512);                           \
    } while (0)

    // prologue: tiles 0 and 1 in flight (FIFO: tile-0 loads retire first)
    STAGE4(b0, 0);
    STAGE4(b1, 32);

    const int slot = (quad ^ ((l15 >> 1) & 3)) << 3;   // read-side elem off
    for (int it = 0; it < NST; ++it) {
        // wait for OWN current-tile loads only; tile it+1 stays in flight
        if (it < NST - 1)
            asm volatile("s_waitcnt vmcnt(%0)" :: "i"(LPW) : "memory");
        else
            asm volatile("s_waitcnt vmcnt(0)" ::: "memory");
        // after this barrier: all waves' tile-it loads are LDS-visible AND
        // (thanks to the lgkmcnt(0) below) all waves' reads of the buffer
        // b2 points at have EXECUTED -> safe to overwrite.
        asm volatile("s_barrier" ::: "memory");

        if (it + 2 < NST)
            STAGE4(b2, (it + 2) * 32);

        bf16x8 af[BM / 32], bf[BN / 32];
        for (int i = 0; i < BM / 32; ++i) {
            int row = wm * (BM / 2) + i * 16 + l15;
            af[i] = lds_frag(b0 + row * 32 + slot);
        }
        for (int j = 0; j < BN / 32; ++j) {
            int row = wn * (BN / 2) + j * 16 + l15;
            bf[j] = lds_frag(b0 + TA + row * 32 + slot);
        }
        for (int i = 0; i < BM / 32; ++i)
            for (int j = 0; j < BN / 32; ++j)
                acc[i][j] = __builtin_amdgcn_mfma_f32_16x16x32_bf16(
                    af[i], bf[j], acc[i][j], 0, 0, 0);

        // RACE FIX: force this wave's ds_reads to have EXECUTED before it
        // can reach the next raw s_barrier (compiler may sink MFMAs+their
        // lgkmcnt waits past asm barriers; ds_read issue-order alone does
        // not pin execution).  Nearly free: reads feed this step's MFMAs.
        asm volatile("s_waitcnt lgkmcnt(0)" ::: "memory");

        ushort_t* t = b0; b0 = b1; b1 = b2; b2 = t;    // rotate ring
    }
#undef STAGE4
    __syncthreads();   // protect epilogue LDS reuse (nothing left to drain)
}

// Fused Q/K/V projections: z = 0 (Q, scaled), 1 (K), 2 (V, transposed out).
// 1D grid 768, XCD-swizzled; 48KB ring + transpose share -> 3 blocks/CU.
__global__ __launch_bounds__(256, 3) void proj3(
    const ushort_t* __restrict__ Qb, const ushort_t* __restrict__ KVb,
    const ushort_t* __restrict__ qwb, const ushort_t* __restrict__ kwb,
    const ushort_t* __restrict__ vwb,
    const float* __restrict__ q_b, const float* __restrict__ k_b,
    const float* __restrict__ v_b,
    ushort_t* __restrict__ Qp, ushort_t* __restrict__ Kp,
    ushort_t* __restrict__ VpT)
{
    __shared__ __align__(1024) ushort_t sLDS[24576];   // 49152 B (3 x 16KB)

    const int lb = xcd_swz(blockIdx.x, 768);
    const int z  = lb >> 8;                // 0..2
    const int r  = lb & 255;
    const int m0 = (r >> 3) * 128;
    const int n0 = (r & 7) * 128;

    const ushort_t* A = z ? KVb : Qb;
    const ushort_t* W = (z == 0) ? qwb : (z == 1 ? kwb : vwb);
    const float* bias = (z == 0) ? q_b : (z == 1 ? k_b : v_b);
    const int tid = threadIdx.x;

    f32x4 acc[4][4] = {};
    gemm_core4<128, 128>(A, W, m0, n0, tid, acc, sLDS);

    const int lane = tid & 63, quad = lane >> 4, l15 = lane & 15;
    const int wm = (tid >> 6) >> 1, wn = (tid >> 6) & 1;

    if (z == 2) {
        // V^T epilogue: transpose 128x128 C-tile through LDS, coalesced out.
        const int TSTR = 136;                // row stride: 272B, 16B-aligned
        for (int j = 0; j < 4; ++j) {
            int col = wn * 64 + j * 16 + l15;           // tile-local n
            float bj = bias[n0 + col];
            for (int i = 0; i < 4; ++i) {
                int row = wm * 64 + i * 16 + quad * 4;  // tile-local m
                ushort4v o4;
                for (int r2 = 0; r2 < 4; ++r2) o4[r2] = fcvt(acc[i][j][r2] + bj);
                *(ushort4v*)(sLDS + col * TSTR + row) = o4;
            }
        }
        __syncthreads();
        const int vrow = tid >> 1;           // 0..127  (V^T row = tile col)
        const int vc   = (tid & 1) * 64;
        ushort_t* dst = VpT + (size_t)(n0 + vrow) * SEQ + m0 + vc;
        const ushort_t* src = sLDS + vrow * TSTR + vc;
        for (int k = 0; k < 8; ++k)
            *(ushort8*)(dst + k * 8) = *(const ushort8*)(src + k * 8);
    } else {
        const float scale = (z == 0) ? QSCALE : 1.0f;
        ushort_t* C = z ? Kp : Qp;
        for (int j = 0; j < 4; ++j) {
            int col = n0 + wn * 64 + j * 16 + l15;
            float bj = bias[col];
            for (int i = 0; i < 4; ++i) {
                int row = m0 + wm * 64 + i * 16 + quad * 4;
                for (int r2 = 0; r2 < 4; ++r2)
                    C[(size_t)(row + r2) * DIM + col] =
                        fcvt((acc[i][j][r2] + bj) * scale);
            }
        }
    }
}

// O projection: f32 output.  64x64 tile, BK=32, 24KB ring -> 4 blocks/CU.
// 1D grid 1024, XCD-swizzled.
__global__ __launch_bounds__(256, 4) void gemm_out(
    const ushort_t* __restrict__ A, const ushort_t* __restrict__ W,
    const float* __restrict__ bias, float* __restrict__ C)
{
    __shared__ __align__(1024) ushort_t sLDS[12288];   // 24576 B (3 x 8KB)

    const int lb = xcd_swz(blockIdx.x, 1024);
    const int m0 = (lb >> 4) * 64;
    const int n0 = (lb & 15) * 64;
    const int tid = threadIdx.x;

    f32x4 acc[2][2] = {};
    gemm_core4<64, 64>(A, W, m0, n0, tid, acc, sLDS);

    const int lane = tid & 63, quad = lane >> 4, l15 = lane & 15;
    const int wm = (tid >> 6) >> 1, wn = (tid >> 6) & 1;
    for (int j = 0; j < 2; ++j) {
        int col = n0 + wn * 32 + j * 16 + l15;
        float bj = bias[col];
        for (int i = 0; i < 2; ++i) {
            int row = m0 + wm * 32 + i * 16 + quad * 4;
            for (int r = 0; r < 4; ++r)
                C[(size_t)(row + r) * DIM + col] = acc[i][j][r] + bj;
        }
    }
}

// ---------------------------------------------------------------------------
// Flash attention — R20 body exactly (green, 97.3us).  4 waves x 32 q rows,
// full KV sweep, swapped QK^T, zero-shift exp2 softmax, P-in-register via
// pk2+permlane32_swap, XOR-swizzled K/V tiles, register-prefetch double
// buffer, 1 barrier/iter (safe: __syncthreads drains lgkmcnt+vmcnt).
// 1D grid 512 + XCD swizzle.
// ---------------------------------------------------------------------------
#define TILE 4096                  // elems per 64x64 bf16 tile
#define BUFE (2 * TILE)            // K tile + V tile per buffer
__global__ __launch_bounds__(256, 2) void attn_kernel(
    const ushort_t* __restrict__ Q, const ushort_t* __restrict__ K,
    const ushort_t* __restrict__ VT, ushort_t* __restrict__ O)
{
    __shared__ __align__(16) ushort_t sB[2 * BUFE];   // 32768 B

    const int lb   = xcd_swz(blockIdx.x, 512);
    const int h    = lb >> 5;
    const int qblk = lb & 31;

    const int tid  = threadIdx.x;
    const int w    = tid >> 6;
    const int lane = tid & 63;
    const int l31  = lane & 31;
    const int hi   = lane >> 5;
    const int q0   = qblk * 128 + w * 32;
    const int hHD  = h * HD;

    const int srow0 = tid >> 3;
    const int srow1 = srow0 + 32;
    const int sch   = (tid & 7) << 3;
    const ushort_t* Kg0 = K  + (size_t)srow0 * DIM + hHD + sch;
    const ushort_t* Kg1 = K  + (size_t)srow1 * DIM + hHD + sch;
    const ushort_t* Vg0 = VT + (size_t)(hHD + srow0) * SEQ + sch;
    const ushort_t* Vg1 = VT + (size_t)(hHD + srow1) * SEQ + sch;
    const int lk0 = swz(srow0, sch), lk1 = swz(srow1, sch);

    const ushort_t* qb = Q + (size_t)(q0 + l31) * DIM + hHD + hi * 8;
    bf16x8 qf[4];
    for (int ks = 0; ks < 4; ++ks)
        qf[ks] = frag_of(*(const ushort8*)(qb + ks * 16));

    *(ushort8*)(sB + lk0)        = *(const ushort8*)(Kg0);
    *(ushort8*)(sB + lk1)        = *(const ushort8*)(Kg1);
    *(ushort8*)(sB + TILE + lk0) = *(const ushort8*)(Vg0);
    *(ushort8*)(sB + TILE + lk1) = *(const ushort8*)(Vg1);
    __syncthreads();

    f32x16 oacc[2] = {};
    float l_i = 0.f;

    for (int it = 0; it < SEQ / 64; ++it) {
        const int cur = it & 1;
        const int kvn = (it + 1) * 64;
        ushort_t* bK = sB + cur * BUFE;
        ushort_t* bV = bK + TILE;

        ushort8 gk0, gk1, gv0, gv1;
        if (kvn < SEQ) {
            gk0 = *(const ushort8*)(Kg0 + (size_t)kvn * DIM);
            gk1 = *(const ushort8*)(Kg1 + (size_t)kvn * DIM);
            gv0 = *(const ushort8*)(Vg0 + kvn);
            gv1 = *(const ushort8*)(Vg1 + kvn);
        }

        bf16x8 kf[8], vf[8];
        for (int t = 0; t < 2; ++t)
            for (int ks = 0; ks < 4; ++ks) {
                int r = t * 32 + l31;
                kf[t * 4 + ks] = lds_frag(bK + swz(r, ks * 16 + hi * 8));
            }
        for (int dt = 0; dt < 2; ++dt)
            for (int ks = 0; ks < 4; ++ks) {
                int r = dt * 32 + l31;
                vf[ks * 2 + dt] = lds_frag(bV + swz(r, ks * 16 + hi * 8));
            }

        // S^T = K Q^T : lane l31 = q col, regs = kv rows
        f32x16 sacc[2] = {};
        for (int t = 0; t < 2; ++t)
            for (int ks = 0; ks < 4; ++ks)
                sacc[t] = __builtin_amdgcn_mfma_f32_32x32x16_bf16(
                    kf[t * 4 + ks], qf[ks], sacc[t], 0, 0, 0);

        float lp = 0.f;
        for (int t = 0; t < 2; ++t)
            for (int r = 0; r < 16; ++r) {
                float p = __builtin_amdgcn_exp2f(sacc[t][r]);
                sacc[t][r] = p;
                lp += p;
            }
        l_i += lp + __shfl_xor(lp, 32);

        // In-register P -> PV B-fragment (see R13 derivation).
        for (int ks = 0; ks < 4; ++ks) {
            const int t = ks >> 1, s8 = (ks & 1) * 8;
            unsigned p00 = pk2(sacc[t][s8 + 0], sacc[t][s8 + 1]);
            unsigned p01 = pk2(sacc[t][s8 + 2], sacc[t][s8 + 3]);
            unsigned p10 = pk2(sacc[t][s8 + 4], sacc[t][s8 + 5]);
            unsigned p11 = pk2(sacc[t][s8 + 6], sacc[t][s8 + 7]);
            plswap(p00, p10);
            plswap(p01, p11);
            uint4v wv; wv[0] = p00; wv[1] = p01; wv[2] = p10; wv[3] = p11;
            bf16x8 pf = __builtin_bit_cast(bf16x8, wv);
            for (int dt = 0; dt < 2; ++dt)
                oacc[dt] = __builtin_amdgcn_mfma_f32_32x32x16_bf16(
                    vf[ks * 2 + dt], pf, oacc[dt], 0, 0, 0);
        }

        if (kvn < SEQ) {
            ushort_t* nB = sB + (cur ^ 1) * BUFE;
            *(ushort8*)(nB + lk0)        = gk0;
            *(ushort8*)(nB + lk1)        = gk1;
            *(ushort8*)(nB + TILE + lk0) = gv0;
            *(ushort8*)(nB + TILE + lk1) = gv1;
        }
        __syncthreads();
    }

    float inv = 1.f / l_i;
    int qrow = q0 + l31;
    for (int dt = 0; dt < 2; ++dt)
        for (int g = 0; g < 4; ++g) {
            ushort4v o4;
            for (int r = 0; r < 4; ++r) o4[r] = fcvt(oacc[dt][g * 4 + r] * inv);
            *(ushort4v*)(O + (size_t)qrow * DIM + hHD + dt * 32 + g * 8 + hi * 4) = o4;
        }
}

// ---------------------------------------------------------------------------
extern "C" void kernel_launch(void* const* d_in, const int* in_sizes, int n_in,
                              void* d_out, int out_size, void* d_ws, size_t ws_size,
                              hipStream_t stream)
{
    const float* q   = (const float*)d_in[0];
    const float* kv  = (const float*)d_in[1];
    const float* q_w = (const float*)d_in[2];
    const float* q_b = (const float*)d_in[3];
    const float* k_w = (const float*)d_in[4];
    const float* k_b = (const float*)d_in[5];
    const float* v_w = (const float*)d_in[6];
    const float* v_b = (const float*)d_in[7];
    const float* o_w = (const float*)d_in[8];
    const float* o_b = (const float*)d_in[9];
    float* out = (float*)d_out;

    const size_t SD = (size_t)SEQ * DIM;
    const size_t WW = (size_t)DIM * DIM;
    ushort_t* Qp  = (ushort_t*)d_ws;          // bf16, pre-scaled by QSCALE
    ushort_t* Kp  = Qp + SD;
    ushort_t* VpT = Kp + SD;                  // V^T: [DIM][SEQ]
    ushort_t* AO  = VpT + SD;                 // attention out; aliases Qb
    ushort_t* Qb  = AO;                       // bf16(q) — dead before AO write
    ushort_t* KVb = AO + SD;
    ushort_t* qwb = KVb + SD;
    ushort_t* kwb = qwb + WW;
    ushort_t* vwb = kwb + WW;
    ushort_t* owb = vwb + WW;

    cvt2<<<dim3((unsigned)(SD / 8 / 256), 2), 256, 0, stream>>>(
        q, Qb, kv, KVb, (int)(SD / 8));
    cvt4<<<dim3((unsigned)(WW / 8 / 256), 4), 256, 0, stream>>>(
        q_w, qwb, k_w, kwb, v_w, vwb, o_w, owb, (int)(WW / 8));

    proj3<<<dim3(768), 256, 0, stream>>>(
        Qb, KVb, qwb, kwb, vwb, q_b, k_b, v_b, Qp, Kp, VpT);
    attn_kernel<<<dim3(512), 256, 0, stream>>>(Qp, Kp, VpT, AO);
    gemm_out<<<dim3(1024), 256, 0, stream>>>(AO, owb, o_b, out);
}